// Round 2
// baseline (206.205 us; speedup 1.0000x reference)
//
#include <hip/hip_runtime.h>
#include <math.h>

// PPO loss with GAE.  B=4096 rows, T=2048 steps, fp32 inputs.
// Inputs: 0 rewards(B,T) 1 values(B,T+1) 2 ref_probs(UNUSED) 3 old_probs(B,T)
//         4 curr_probs(B,T) 5 masks(B,T)
// Output: 4 floats: total, ppo, 0.5*value_loss, 0.01*entropy_loss
//
// R7 == R6 resubmit (R6 bench was an infra flake: container failed, no run).
// R6: gae was latency/issue-bound (VALUBusy 10%, HBM 20%, VGPR=40 -> compiler
// serialized the 26 up-front loads; 18 of them scalar because values rows
// (stride 2049 floats) are never 16B-aligned).
//  (1) values: aligned 3x float4 window [t0-ofs, t0-ofs+12) + wave-uniform
//      extraction branch (ofs = row&3 is block-uniform). 9 scalar loads -> 3
//      coalesced dwordx4 per row; 26 loads/thread -> 14, all x16B.
//  (2) ppo: 8 elems/thread (was 16), 5 vector loads in flight, 4096 blocks,
//      VGPR ~40 -> full 8 waves/SIMD streaming occupancy.
// adv values bitwise unchanged vs R5 (same arithmetic, new load path).

#define GAMMA     0.99f
#define LAM       0.95f
#define CLIP_LO   0.8f
#define CLIP_HI   1.2f
#define EPSF      1e-9f

constexpr int BB = 4096;
constexpr int TT = 2048;
constexpr long long NN = (long long)BB * TT;   // 8388608
constexpr int GAE_BLOCKS = BB / 2;             // 2048, 2 rows/block
constexpr int PPO_BLOCKS = 4096;               // 8 elems/thread

// ws layout:
//  [0,32)           stats: float mean, float inv_std_eps, double sum_adv2
//  [64, 64+16K)     gae partials: 2048 x float2
//  [16448, +32K)    ppo partials: 4096 x float2
//  [49216, +16.8M)  adv in bf16 (uint4-aligned)
struct Stats { float mean; float inv; double sum2; };
static constexpr size_t GAE_PART_OFF = 64;
static constexpr size_t PPO_PART_OFF = GAE_PART_OFF + GAE_BLOCKS * sizeof(float2); // 16448
static constexpr size_t ADV_OFF      = PPO_PART_OFF + PPO_BLOCKS * sizeof(float2); // 49216 (16-aligned)

__device__ __forceinline__ unsigned bf16_rne(float x) {
    unsigned u = __float_as_uint(x);
    u += 0x7FFFu + ((u >> 16) & 1u);
    return u >> 16;
}

// ---------------------------------------------------------------- K1: GAE scan
__global__ __launch_bounds__(256, 4) void gae_kernel(
    const float* __restrict__ rewards,
    const float* __restrict__ values,
    const float* __restrict__ masks,
    uint4* __restrict__ advb,          // bf16 x8 per uint4
    float2* __restrict__ partials)
{
    const int tid  = threadIdx.x;
    const int lane = tid & 63;
    const int wave = tid >> 6;
    const int t0   = tid * 8;
    const int row0 = blockIdx.x * 2;
    const int row1 = row0 + 1;

    __shared__ float2 wTa[4], wTb[4];
    __shared__ float  wr1[4], wr2[4];

    // ---- rewards/masks: aligned float4 direct (row stride 2048 floats)
    const float* ra = rewards + (size_t)row0 * TT;
    const float* ma = masks   + (size_t)row0 * TT;
    const float* rb = rewards + (size_t)row1 * TT;
    const float* mb = masks   + (size_t)row1 * TT;

    // ---- values: aligned 3x float4 window, block-uniform misalignment ofs
    const size_t vwA = (size_t)row0 * (TT + 1);    // word index of row start
    const size_t vwB = (size_t)row1 * (TT + 1);
    const int ofsA = (int)(vwA & 3);               // row0 & 3, in {0,2}
    const int ofsB = (int)(vwB & 3);               // row1 & 3, in {1,3}
    const float4* vA4 = (const float4*)(values + (vwA & ~(size_t)3));
    const float4* vB4 = (const float4*)(values + (vwB & ~(size_t)3));

    // ---- issue all 14 vector loads up front (independent)
    float4 ra0 = *(const float4*)(ra + t0);
    float4 ra1 = *(const float4*)(ra + t0 + 4);
    float4 ma0 = *(const float4*)(ma + t0);
    float4 ma1 = *(const float4*)(ma + t0 + 4);
    float4 rb0 = *(const float4*)(rb + t0);
    float4 rb1 = *(const float4*)(rb + t0 + 4);
    float4 mb0 = *(const float4*)(mb + t0);
    float4 mb1 = *(const float4*)(mb + t0 + 4);
    float4 fa0 = vA4[2 * tid];
    float4 fa1 = vA4[2 * tid + 1];
    float4 fa2 = vA4[2 * tid + 2];   // window covers words [t0, t0+11] of shifted base
    float4 fb0 = vB4[2 * tid];
    float4 fb1 = vB4[2 * tid + 1];
    float4 fb2 = vB4[2 * tid + 2];
    // OOB check: worst case row 4095 (ofs=3): last word read = 4095*2049-3+2051
    // = 8392703 = last element of values. In bounds for all rows.

    // ---- extract the 9 needed values per row (wave-uniform branch, static idx)
    float va[9], vb[9];
    {
        float f[12] = {fa0.x, fa0.y, fa0.z, fa0.w, fa1.x, fa1.y, fa1.z, fa1.w,
                       fa2.x, fa2.y, fa2.z, fa2.w};
        if (ofsA == 0) {
#pragma unroll
            for (int j = 0; j < 9; ++j) va[j] = f[j];
        } else {        // ofsA == 2 (row0 even)
#pragma unroll
            for (int j = 0; j < 9; ++j) va[j] = f[j + 2];
        }
    }
    {
        float f[12] = {fb0.x, fb0.y, fb0.z, fb0.w, fb1.x, fb1.y, fb1.z, fb1.w,
                       fb2.x, fb2.y, fb2.z, fb2.w};
        if (ofsB == 1) {
#pragma unroll
            for (int j = 0; j < 9; ++j) vb[j] = f[j + 1];
        } else {        // ofsB == 3 (row1 odd)
#pragma unroll
            for (int j = 0; j < 9; ++j) vb[j] = f[j + 3];
        }
    }

    float rA[8] = {ra0.x, ra0.y, ra0.z, ra0.w, ra1.x, ra1.y, ra1.z, ra1.w};
    float mA[8] = {ma0.x, ma0.y, ma0.z, ma0.w, ma1.x, ma1.y, ma1.z, ma1.w};
    float rB[8] = {rb0.x, rb0.y, rb0.z, rb0.w, rb1.x, rb1.y, rb1.z, rb1.w};
    float mB[8] = {mb0.x, mb0.y, mb0.z, mb0.w, mb1.x, mb1.y, mb1.z, mb1.w};

    // ---- per-row chunk-local reverse affine scans (unchanged, verified R4/R5)
    float laA[8], SA[8], laB[8], SB[8];
    {
        float d[8], c[8];
#pragma unroll
        for (int j = 0; j < 8; ++j) {
            d[j] = rA[j] + GAMMA * va[j + 1] * mA[j] - va[j];
            c[j] = (GAMMA * LAM) * mA[j];
        }
        laA[7] = d[7]; SA[7] = c[7];
#pragma unroll
        for (int j = 6; j >= 0; --j) { laA[j] = d[j] + c[j] * laA[j + 1]; SA[j] = c[j] * SA[j + 1]; }
    }
    {
        float d[8], c[8];
#pragma unroll
        for (int j = 0; j < 8; ++j) {
            d[j] = rB[j] + GAMMA * vb[j + 1] * mB[j] - vb[j];
            c[j] = (GAMMA * LAM) * mB[j];
        }
        laB[7] = d[7]; SB[7] = c[7];
#pragma unroll
        for (int j = 6; j >= 0; --j) { laB[j] = d[j] + c[j] * laB[j + 1]; SB[j] = c[j] * SB[j + 1]; }
    }

    // ---- wave-level suffix scans of affine fns (verified in R4)
    float Aa = SA[0], Ba = laA[0];
    float Ab = SB[0], Bb = laB[0];
#pragma unroll
    for (int d = 1; d < 64; d <<= 1) {
        float A2a = __shfl_down(Aa, d, 64), B2a = __shfl_down(Ba, d, 64);
        float A2b = __shfl_down(Ab, d, 64), B2b = __shfl_down(Bb, d, 64);
        if (lane + d < 64) {
            Ba = Ba + Aa * B2a;  Aa = Aa * A2a;
            Bb = Bb + Ab * B2b;  Ab = Ab * A2b;
        }
    }
    if (lane == 0) { wTa[wave] = make_float2(Aa, Ba); wTb[wave] = make_float2(Ab, Bb); }
    __syncthreads();
    float Ca = 0.0f, Cb = 0.0f;
    for (int ww = 3; ww > wave; --ww) {
        Ca = wTa[ww].y + wTa[ww].x * Ca;
        Cb = wTb[ww].y + wTb[ww].x * Cb;
    }
    float A1a = __shfl_down(Aa, 1, 64), B1a = __shfl_down(Ba, 1, 64);
    float A1b = __shfl_down(Ab, 1, 64), B1b = __shfl_down(Bb, 1, 64);
    float carA = (lane < 63) ? (B1a + A1a * Ca) : Ca;
    float carB = (lane < 63) ? (B1b + A1b * Cb) : Cb;

    // ---- final adv, fp32 sums, bf16 pack + store
    float s1 = 0.f, s2 = 0.f;
    unsigned ha[8], hb[8];
#pragma unroll
    for (int j = 0; j < 8; ++j) {
        float a = laA[j] + SA[j] * carA;
        s1 += a; s2 += a * a;
        ha[j] = bf16_rne(a);
        float b = laB[j] + SB[j] * carB;
        s1 += b; s2 += b * b;
        hb[j] = bf16_rne(b);
    }
    uint4 pa = {ha[0] | (ha[1] << 16), ha[2] | (ha[3] << 16),
                ha[4] | (ha[5] << 16), ha[6] | (ha[7] << 16)};
    uint4 pb = {hb[0] | (hb[1] << 16), hb[2] | (hb[3] << 16),
                hb[4] | (hb[5] << 16), hb[6] | (hb[7] << 16)};
    advb[row0 * 256 + tid] = pa;      // 8 bf16 = 16B per thread, coalesced
    advb[row1 * 256 + tid] = pb;

    // ---- block reduce -> one float2 per block
#pragma unroll
    for (int off = 32; off > 0; off >>= 1) {
        s1 += __shfl_down(s1, off, 64);
        s2 += __shfl_down(s2, off, 64);
    }
    if (lane == 0) { wr1[wave] = s1; wr2[wave] = s2; }
    __syncthreads();
    if (tid == 0) {
        float2 p = {wr1[0] + wr1[1] + wr1[2] + wr1[3],
                    wr2[0] + wr2[1] + wr2[2] + wr2[3]};
        partials[blockIdx.x] = p;
    }
}

// ------------------------------------- K2: reduce gae partials -> mean, inv_std
__global__ __launch_bounds__(256) void finalize_stats(
    const float2* __restrict__ gp, Stats* __restrict__ stats)
{
    const int tid = threadIdx.x;
    __shared__ double l1[256], l2[256];
    double s1 = 0.0, s2 = 0.0;
    for (int i = tid; i < GAE_BLOCKS; i += 256) {
        float2 p = gp[i];
        s1 += (double)p.x;
        s2 += (double)p.y;
    }
    l1[tid] = s1; l2[tid] = s2;
    __syncthreads();
    for (int st = 128; st > 0; st >>= 1) {
        if (tid < st) { l1[tid] += l1[tid + st]; l2[tid] += l2[tid + st]; }
        __syncthreads();
    }
    if (tid == 0) {
        double S1 = l1[0], S2 = l2[0];
        double mean = S1 / (double)NN;
        double var  = (S2 - S1 * S1 / (double)NN) / (double)(NN - 1); // ddof=1
        stats->mean = (float)mean;
        stats->inv  = (float)(1.0 / (sqrt(var) + 1e-9));
        stats->sum2 = S2;
    }
}

// ------------------------------------------------- K3: ppo surrogate + entropy
__global__ __launch_bounds__(256, 8) void ppo_kernel(
    const float* __restrict__ adv_bf16,   // raw bf16 pairs, read as uint4
    const float* __restrict__ oldp,
    const float* __restrict__ currp,
    const Stats* __restrict__ stats,
    float2* __restrict__ partials)
{
    const float mean = stats->mean;
    const float inv  = stats->inv;
    const int tid = threadIdx.x;
    const int g   = blockIdx.x * 256 + tid;     // uint4 index: 8 elems/thread

    const uint4*  a4 = (const uint4*)adv_bf16;
    const float4* o4 = (const float4*)oldp;
    const float4* c4 = (const float4*)currp;

    // 5 vector loads in flight, ~40 VGPR -> 8 waves/SIMD
    uint4  A  = a4[g];
    float4 O0 = o4[2 * g], O1 = o4[2 * g + 1];
    float4 C0 = c4[2 * g], C1 = c4[2 * g + 1];

    float av[8] = {__uint_as_float(A.x << 16), __uint_as_float(A.x & 0xFFFF0000u),
                   __uint_as_float(A.y << 16), __uint_as_float(A.y & 0xFFFF0000u),
                   __uint_as_float(A.z << 16), __uint_as_float(A.z & 0xFFFF0000u),
                   __uint_as_float(A.w << 16), __uint_as_float(A.w & 0xFFFF0000u)};
    float ov[8] = {O0.x, O0.y, O0.z, O0.w, O1.x, O1.y, O1.z, O1.w};
    float cv[8] = {C0.x, C0.y, C0.z, C0.w, C1.x, C1.y, C1.z, C1.w};

    float sm = 0.f, se = 0.f;
#pragma unroll
    for (int j = 0; j < 8; ++j) {
        float an    = (av[j] - mean) * inv;
        float ratio = cv[j] * __builtin_amdgcn_rcpf(ov[j] + EPSF);
        float rc    = fminf(fmaxf(ratio, CLIP_LO), CLIP_HI);
        sm += fminf(ratio * an, rc * an);
        se += cv[j] * __logf(cv[j] + EPSF);
    }

#pragma unroll
    for (int off = 32; off > 0; off >>= 1) {
        sm += __shfl_down(sm, off, 64);
        se += __shfl_down(se, off, 64);
    }
    __shared__ float w1[4], w2[4];
    const int wave = tid >> 6, lane = tid & 63;
    if (lane == 0) { w1[wave] = sm; w2[wave] = se; }
    __syncthreads();
    if (tid == 0) {
        float2 p = {w1[0] + w1[1] + w1[2] + w1[3],
                    w2[0] + w2[1] + w2[2] + w2[3]};
        partials[blockIdx.x] = p;
    }
}

// --------------------------------- K4: reduce ppo partials -> 4 output scalars
__global__ __launch_bounds__(256) void finalize_out(
    const float2* __restrict__ pp,
    const Stats* __restrict__ stats,
    float* __restrict__ out)
{
    const int tid = threadIdx.x;
    __shared__ double l1[256], l2[256];
    double s1 = 0.0, s2 = 0.0;
    for (int i = tid; i < PPO_BLOCKS; i += 256) {
        float2 p = pp[i];
        s1 += (double)p.x;
        s2 += (double)p.y;
    }
    l1[tid] = s1; l2[tid] = s2;
    __syncthreads();
    for (int st = 128; st > 0; st >>= 1) {
        if (tid < st) { l1[tid] += l1[tid + st]; l2[tid] += l2[tid + st]; }
        __syncthreads();
    }
    if (tid == 0) {
        double invN = 1.0 / (double)NN;
        double vl   = 0.5  * (stats->sum2 * invN);   // 0.5 * mean(raw_adv^2)
        double ppo  = -(l1[0] * invN);
        double ent  = -0.01 * (l2[0] * invN);
        out[0] = (float)(ppo + vl + ent);
        out[1] = (float)ppo;
        out[2] = (float)vl;
        out[3] = (float)ent;
    }
}

extern "C" void kernel_launch(void* const* d_in, const int* in_sizes, int n_in,
                              void* d_out, int out_size, void* d_ws, size_t ws_size,
                              hipStream_t stream) {
    const float* rewards = (const float*)d_in[0];
    const float* values  = (const float*)d_in[1];
    // d_in[2] = ref_probs: unused by the reference
    const float* oldp    = (const float*)d_in[3];
    const float* currp   = (const float*)d_in[4];
    const float* masks   = (const float*)d_in[5];

    Stats*  stats = (Stats*)d_ws;
    float2* gaep  = (float2*)((char*)d_ws + GAE_PART_OFF);
    float2* ppop  = (float2*)((char*)d_ws + PPO_PART_OFF);
    uint4*  advb  = (uint4*)((char*)d_ws + ADV_OFF);
    float*  out   = (float*)d_out;

    gae_kernel<<<GAE_BLOCKS, 256, 0, stream>>>(rewards, values, masks, advb, gaep);
    finalize_stats<<<1, 256, 0, stream>>>(gaep, stats);
    ppo_kernel<<<PPO_BLOCKS, 256, 0, stream>>>((const float*)advb, oldp, currp, stats, ppop);
    finalize_out<<<1, 256, 0, stream>>>(ppop, stats, out);
}

// Round 3
// 204.595 us; speedup vs baseline: 1.0079x; 1.0079x over previous
//
#include <hip/hip_runtime.h>
#include <math.h>

// PPO loss with GAE.  B=4096 rows, T=2048 steps, fp32 inputs.
// Inputs: 0 rewards(B,T) 1 values(B,T+1) 2 ref_probs(UNUSED) 3 old_probs(B,T)
//         4 curr_probs(B,T) 5 masks(B,T)
// Output: 4 floats: total, ppo, 0.5*value_loss, 0.01*entropy_loss
//
// R8: R6/R7 failed (VGPR stayed 40 -> compiler re-serialized the up-front
// loads; occupancy only 40% so no TLP cover either; gae latency-bound at
// 42us vs ~17us BW floor). This round forces MLP structurally:
//  - gae: 512 persistent blocks, 8 rows/block, ROLLED loop (unroll 1) with
//    2-deep register double-buffer prefetch. Next row's 7 float4 loads are
//    live across the loop back-edge -> compiler cannot sink them; a
//    sched_barrier(0) after each load batch pins issue order.
//  - __launch_bounds__(256,2): VGPR cap 256 so ~130-reg pipeline fits.
//  - 1 row per step (simpler verified scan), 4-way uniform ofs extraction.
// Tell for success: gae VGPR ~130-180, dur ~20us. ppo unchanged.

#define GAMMA     0.99f
#define LAM       0.95f
#define CLIP_LO   0.8f
#define CLIP_HI   1.2f
#define EPSF      1e-9f

constexpr int BB = 4096;
constexpr int TT = 2048;
constexpr long long NN = (long long)BB * TT;   // 8388608
constexpr int GAE_BLOCKS = 512;                // persistent, 8 rows each
constexpr int ROWS_PER_BLOCK = 8;
constexpr int PPO_BLOCKS = 4096;               // 8 elems/thread

// ws layout:
//  [0,32)          stats: float mean, float inv_std_eps, double sum_adv2
//  [64, +4K)       gae partials: 512 x float2
//  [4160, +32K)    ppo partials: 4096 x float2
//  [36928, +16.8M) adv in bf16 (uint4-aligned; 36928 % 16 == 0)
struct Stats { float mean; float inv; double sum2; };
static constexpr size_t GAE_PART_OFF = 64;
static constexpr size_t PPO_PART_OFF = GAE_PART_OFF + GAE_BLOCKS * sizeof(float2); // 4160
static constexpr size_t ADV_OFF      = PPO_PART_OFF + PPO_BLOCKS * sizeof(float2); // 36928

__device__ __forceinline__ unsigned bf16_rne(float x) {
    unsigned u = __float_as_uint(x);
    u += 0x7FFFu + ((u >> 16) & 1u);
    return u >> 16;
}

// Issue all 7 vector loads for row r into the given float4 regs.
// values: aligned 3x float4 window starting at (r*2049) & ~3; needed words are
// f[ofs..ofs+8], ofs = r & 3. OOB check: worst case r=4095 (ofs=3), tid=255:
// last word = 4095*2049 - 3 + 2051 = 8392703 = last element of values. OK.
#define LOADROW(r, R0, R1, M0, M1, F0, F1, F2) do {                         \
    const float* _rp = rewards + (size_t)(r) * TT;                          \
    const float* _mp = masks   + (size_t)(r) * TT;                          \
    const size_t _vw = (size_t)(r) * (TT + 1);                              \
    const float4* _v4 = (const float4*)(values + (_vw & ~(size_t)3));       \
    R0 = *(const float4*)(_rp + t0);                                        \
    R1 = *(const float4*)(_rp + t0 + 4);                                    \
    M0 = *(const float4*)(_mp + t0);                                        \
    M1 = *(const float4*)(_mp + t0 + 4);                                    \
    F0 = _v4[2 * tid];                                                      \
    F1 = _v4[2 * tid + 1];                                                  \
    F2 = _v4[2 * tid + 2];                                                  \
} while (0)

// Full single-row GAE step: extraction, chunk scan, wave scan, cross-wave
// carry (verified R4 structure), bf16 pack/store, s1/s2 accumulation.
// PAR selects the LDS parity buffer (static 0/1 at each expansion site).
#define COMPUTE(r, PAR, R0, R1, M0, M1, F0, F1, F2) do {                    \
    float rr[8] = {R0.x, R0.y, R0.z, R0.w, R1.x, R1.y, R1.z, R1.w};         \
    float mm[8] = {M0.x, M0.y, M0.z, M0.w, M1.x, M1.y, M1.z, M1.w};         \
    float ff[12] = {F0.x, F0.y, F0.z, F0.w, F1.x, F1.y, F1.z, F1.w,         \
                    F2.x, F2.y, F2.z, F2.w};                                \
    float vv[9];                                                            \
    const int _ofs = (int)((r) & 3);  /* wave-uniform */                    \
    if (_ofs == 0) {                                                        \
        _Pragma("unroll") for (int j = 0; j < 9; ++j) vv[j] = ff[j];        \
    } else if (_ofs == 1) {                                                 \
        _Pragma("unroll") for (int j = 0; j < 9; ++j) vv[j] = ff[j + 1];    \
    } else if (_ofs == 2) {                                                 \
        _Pragma("unroll") for (int j = 0; j < 9; ++j) vv[j] = ff[j + 2];    \
    } else {                                                                \
        _Pragma("unroll") for (int j = 0; j < 9; ++j) vv[j] = ff[j + 3];    \
    }                                                                       \
    float la[8], S[8];                                                      \
    {                                                                       \
        float d[8], c[8];                                                   \
        _Pragma("unroll") for (int j = 0; j < 8; ++j) {                     \
            d[j] = rr[j] + GAMMA * vv[j + 1] * mm[j] - vv[j];               \
            c[j] = (GAMMA * LAM) * mm[j];                                   \
        }                                                                   \
        la[7] = d[7]; S[7] = c[7];                                          \
        _Pragma("unroll") for (int j = 6; j >= 0; --j) {                    \
            la[j] = d[j] + c[j] * la[j + 1];                                \
            S[j]  = c[j] * S[j + 1];                                        \
        }                                                                   \
    }                                                                       \
    float A = S[0], Bv = la[0];                                             \
    _Pragma("unroll") for (int d2 = 1; d2 < 64; d2 <<= 1) {                 \
        float A2 = __shfl_down(A, d2, 64), B2 = __shfl_down(Bv, d2, 64);    \
        if (lane + d2 < 64) { Bv = Bv + A * B2; A = A * A2; }               \
    }                                                                       \
    if (lane == 0) wT[PAR][wave] = make_float2(A, Bv);                      \
    __syncthreads();                                                        \
    float C = 0.f;                                                          \
    for (int ww = 3; ww > wave; --ww)                                       \
        C = wT[PAR][ww].y + wT[PAR][ww].x * C;                              \
    float A1 = __shfl_down(A, 1, 64), B1 = __shfl_down(Bv, 1, 64);          \
    float car = (lane < 63) ? (B1 + A1 * C) : C;                            \
    unsigned hh[8];                                                         \
    _Pragma("unroll") for (int j = 0; j < 8; ++j) {                         \
        float a = la[j] + S[j] * car;                                       \
        s1 += a; s2 += a * a;                                               \
        hh[j] = bf16_rne(a);                                                \
    }                                                                       \
    uint4 pk = {hh[0] | (hh[1] << 16), hh[2] | (hh[3] << 16),               \
                hh[4] | (hh[5] << 16), hh[6] | (hh[7] << 16)};              \
    advb[(size_t)(r) * 256 + tid] = pk;                                     \
} while (0)

// ---------------------------------------------------------------- K1: GAE scan
__global__ __launch_bounds__(256, 2) void gae_kernel(
    const float* __restrict__ rewards,
    const float* __restrict__ values,
    const float* __restrict__ masks,
    uint4* __restrict__ advb,          // bf16 x8 per uint4
    float2* __restrict__ partials)
{
    const int tid  = threadIdx.x;
    const int lane = tid & 63;
    const int wave = tid >> 6;
    const int t0   = tid * 8;
    const int rbase = blockIdx.x * ROWS_PER_BLOCK;

    __shared__ float2 wT[2][4];        // parity-buffered wave totals
    __shared__ float  wr1[4], wr2[4];

    float s1 = 0.f, s2 = 0.f;

    float4 aR0, aR1, aM0, aM1, aF0, aF1, aF2;   // buffer A
    float4 bR0, bR1, bM0, bM1, bF0, bF1, bF2;   // buffer B

    LOADROW(rbase, aR0, aR1, aM0, aM1, aF0, aF1, aF2);

#pragma unroll 1
    for (int k2 = 0; k2 < ROWS_PER_BLOCK / 2; ++k2) {
        const int r0 = rbase + 2 * k2;
        // prefetch row r0+1 into B, then compute row r0 from A
        LOADROW(r0 + 1, bR0, bR1, bM0, bM1, bF0, bF1, bF2);
        __builtin_amdgcn_sched_barrier(0);
        COMPUTE(r0, 0, aR0, aR1, aM0, aM1, aF0, aF1, aF2);
        // prefetch row r0+2 into A (last trip: harmless in-range reload),
        // then compute row r0+1 from B
        const int rn = (k2 < ROWS_PER_BLOCK / 2 - 1) ? (r0 + 2) : r0;
        LOADROW(rn, aR0, aR1, aM0, aM1, aF0, aF1, aF2);
        __builtin_amdgcn_sched_barrier(0);
        COMPUTE(r0 + 1, 1, bR0, bR1, bM0, bM1, bF0, bF1, bF2);
    }

    // ---- block reduce of row sums -> one float2 per block
#pragma unroll
    for (int off = 32; off > 0; off >>= 1) {
        s1 += __shfl_down(s1, off, 64);
        s2 += __shfl_down(s2, off, 64);
    }
    if (lane == 0) { wr1[wave] = s1; wr2[wave] = s2; }
    __syncthreads();
    if (tid == 0) {
        partials[blockIdx.x] = make_float2(wr1[0] + wr1[1] + wr1[2] + wr1[3],
                                           wr2[0] + wr2[1] + wr2[2] + wr2[3]);
    }
}

// ------------------------------------- K2: reduce gae partials -> mean, inv_std
__global__ __launch_bounds__(256) void finalize_stats(
    const float2* __restrict__ gp, Stats* __restrict__ stats)
{
    const int tid = threadIdx.x;
    __shared__ double l1[256], l2[256];
    double s1 = 0.0, s2 = 0.0;
    for (int i = tid; i < GAE_BLOCKS; i += 256) {
        float2 p = gp[i];
        s1 += (double)p.x;
        s2 += (double)p.y;
    }
    l1[tid] = s1; l2[tid] = s2;
    __syncthreads();
    for (int st = 128; st > 0; st >>= 1) {
        if (tid < st) { l1[tid] += l1[tid + st]; l2[tid] += l2[tid + st]; }
        __syncthreads();
    }
    if (tid == 0) {
        double S1 = l1[0], S2 = l2[0];
        double mean = S1 / (double)NN;
        double var  = (S2 - S1 * S1 / (double)NN) / (double)(NN - 1); // ddof=1
        stats->mean = (float)mean;
        stats->inv  = (float)(1.0 / (sqrt(var) + 1e-9));
        stats->sum2 = S2;
    }
}

// ------------------------------------------------- K3: ppo surrogate + entropy
__global__ __launch_bounds__(256, 8) void ppo_kernel(
    const float* __restrict__ adv_bf16,   // raw bf16 pairs, read as uint4
    const float* __restrict__ oldp,
    const float* __restrict__ currp,
    const Stats* __restrict__ stats,
    float2* __restrict__ partials)
{
    const float mean = stats->mean;
    const float inv  = stats->inv;
    const int tid = threadIdx.x;
    const int g   = blockIdx.x * 256 + tid;     // uint4 index: 8 elems/thread

    const uint4*  a4 = (const uint4*)adv_bf16;
    const float4* o4 = (const float4*)oldp;
    const float4* c4 = (const float4*)currp;

    // 5 vector loads in flight, ~40 VGPR -> 8 waves/SIMD
    uint4  A  = a4[g];
    float4 O0 = o4[2 * g], O1 = o4[2 * g + 1];
    float4 C0 = c4[2 * g], C1 = c4[2 * g + 1];

    float av[8] = {__uint_as_float(A.x << 16), __uint_as_float(A.x & 0xFFFF0000u),
                   __uint_as_float(A.y << 16), __uint_as_float(A.y & 0xFFFF0000u),
                   __uint_as_float(A.z << 16), __uint_as_float(A.z & 0xFFFF0000u),
                   __uint_as_float(A.w << 16), __uint_as_float(A.w & 0xFFFF0000u)};
    float ov[8] = {O0.x, O0.y, O0.z, O0.w, O1.x, O1.y, O1.z, O1.w};
    float cv[8] = {C0.x, C0.y, C0.z, C0.w, C1.x, C1.y, C1.z, C1.w};

    float sm = 0.f, se = 0.f;
#pragma unroll
    for (int j = 0; j < 8; ++j) {
        float an    = (av[j] - mean) * inv;
        float ratio = cv[j] * __builtin_amdgcn_rcpf(ov[j] + EPSF);
        float rc    = fminf(fmaxf(ratio, CLIP_LO), CLIP_HI);
        sm += fminf(ratio * an, rc * an);
        se += cv[j] * __logf(cv[j] + EPSF);
    }

#pragma unroll
    for (int off = 32; off > 0; off >>= 1) {
        sm += __shfl_down(sm, off, 64);
        se += __shfl_down(se, off, 64);
    }
    __shared__ float w1[4], w2[4];
    const int wave = tid >> 6, lane = tid & 63;
    if (lane == 0) { w1[wave] = sm; w2[wave] = se; }
    __syncthreads();
    if (tid == 0) {
        float2 p = {w1[0] + w1[1] + w1[2] + w1[3],
                    w2[0] + w2[1] + w2[2] + w2[3]};
        partials[blockIdx.x] = p;
    }
}

// --------------------------------- K4: reduce ppo partials -> 4 output scalars
__global__ __launch_bounds__(256) void finalize_out(
    const float2* __restrict__ pp,
    const Stats* __restrict__ stats,
    float* __restrict__ out)
{
    const int tid = threadIdx.x;
    __shared__ double l1[256], l2[256];
    double s1 = 0.0, s2 = 0.0;
    for (int i = tid; i < PPO_BLOCKS; i += 256) {
        float2 p = pp[i];
        s1 += (double)p.x;
        s2 += (double)p.y;
    }
    l1[tid] = s1; l2[tid] = s2;
    __syncthreads();
    for (int st = 128; st > 0; st >>= 1) {
        if (tid < st) { l1[tid] += l1[tid + st]; l2[tid] += l2[tid + st]; }
        __syncthreads();
    }
    if (tid == 0) {
        double invN = 1.0 / (double)NN;
        double vl   = 0.5  * (stats->sum2 * invN);   // 0.5 * mean(raw_adv^2)
        double ppo  = -(l1[0] * invN);
        double ent  = -0.01 * (l2[0] * invN);
        out[0] = (float)(ppo + vl + ent);
        out[1] = (float)ppo;
        out[2] = (float)vl;
        out[3] = (float)ent;
    }
}

extern "C" void kernel_launch(void* const* d_in, const int* in_sizes, int n_in,
                              void* d_out, int out_size, void* d_ws, size_t ws_size,
                              hipStream_t stream) {
    const float* rewards = (const float*)d_in[0];
    const float* values  = (const float*)d_in[1];
    // d_in[2] = ref_probs: unused by the reference
    const float* oldp    = (const float*)d_in[3];
    const float* currp   = (const float*)d_in[4];
    const float* masks   = (const float*)d_in[5];

    Stats*  stats = (Stats*)d_ws;
    float2* gaep  = (float2*)((char*)d_ws + GAE_PART_OFF);
    float2* ppop  = (float2*)((char*)d_ws + PPO_PART_OFF);
    uint4*  advb  = (uint4*)((char*)d_ws + ADV_OFF);
    float*  out   = (float*)d_out;

    gae_kernel<<<GAE_BLOCKS, 256, 0, stream>>>(rewards, values, masks, advb, gaep);
    finalize_stats<<<1, 256, 0, stream>>>(gaep, stats);
    ppo_kernel<<<PPO_BLOCKS, 256, 0, stream>>>((const float*)advb, oldp, currp, stats, ppop);
    finalize_out<<<1, 256, 0, stream>>>(ppop, stats, out);
}